// Round 3
// baseline (1029.338 us; speedup 1.0000x reference)
//
#include <hip/hip_runtime.h>
#include <hip/hip_bf16.h>

#define FIN 256
#define HID 128
#define BSH 7   // bucket = dst >> 7

typedef __attribute__((ext_vector_type(8))) short short8v;        // bf16x8 MFMA frag
typedef __attribute__((ext_vector_type(4))) float f32x4;          // MFMA acc
typedef __attribute__((ext_vector_type(8))) unsigned short ushort8v;

static __device__ __forceinline__ unsigned short f2bf(float f) {
    unsigned int u = __float_as_uint(f);
    u += 0x7fffu + ((u >> 16) & 1u);   // round-to-nearest-even
    return (unsigned short)(u >> 16);
}
static __device__ __forceinline__ void split_bf16(float f, unsigned short& hi, unsigned short& lo) {
    unsigned int u = __float_as_uint(f);
    unsigned int uh = (u + (0x7fffu + ((u >> 16) & 1u))) & 0xffff0000u;
    hi = (unsigned short)(uh >> 16);
    float fl = f - __uint_as_float(uh);
    unsigned int ul = __float_as_uint(fl);
    lo = (unsigned short)((ul + (0x7fffu + ((ul >> 16) & 1u))) >> 16);
}

// ---------------- degree + bucket histogram ----------------
__global__ void k_deg(const int* __restrict__ dst, int* __restrict__ deg, int* __restrict__ bcnt, int e) {
    int i = blockIdx.x * blockDim.x + threadIdx.x;
    if (i < e) {
        int d = dst[i];
        atomicAdd(&deg[d], 1);
        atomicAdd(&bcnt[d >> BSH], 1);
    }
}

// ---------------- bucket scan (single block, nbk <= 1024) ----------------
__global__ __launch_bounds__(1024) void k_bscan(const int* __restrict__ bcnt, int* __restrict__ bo,
                                                int* __restrict__ bcur, int nbk, int e) {
    __shared__ int sm[1024];
    int t = threadIdx.x;
    int v = (t < nbk) ? bcnt[t] : 0;
    sm[t] = v;
    __syncthreads();
    int acc = v;
    for (int off = 1; off < 1024; off <<= 1) {
        int u = (t >= off) ? sm[t - off] : 0;
        __syncthreads();
        acc += u;
        sm[t] = acc;
        __syncthreads();
    }
    if (t < nbk) { bo[t] = acc - v; bcur[t] = acc - v; }
    if (t == 0) bo[nbk] = e;
}

// ---------------- pair scatter into buckets (write-combined: 782 active regions) ----------------
__global__ void k_pair(const int* __restrict__ src, const int* __restrict__ dst,
                       int* __restrict__ bcur, int2* __restrict__ pairs, int e) {
    int i = blockIdx.x * blockDim.x + threadIdx.x;
    if (i < e) {
        int d = dst[i];
        int p = atomicAdd(&bcur[d >> BSH], 1);
        pairs[p] = make_int2(src[i], d);
    }
}

// ---------------- 3-kernel exclusive scan over deg ----------------
__global__ __launch_bounds__(256) void k_scan1(const int* __restrict__ deg, int* __restrict__ partial,
                                               int* __restrict__ bsum, int n) {
    __shared__ int sm[256];
    int t = threadIdx.x;
    int i = blockIdx.x * 256 + t;
    int v = (i < n) ? deg[i] : 0;
    sm[t] = v;
    __syncthreads();
    int acc = v;
    for (int off = 1; off < 256; off <<= 1) {
        int u = (t >= off) ? sm[t - off] : 0;
        __syncthreads();
        acc += u;
        sm[t] = acc;
        __syncthreads();
    }
    if (i < n) partial[i] = acc;
    if (t == 255) bsum[blockIdx.x] = acc;
}

__global__ __launch_bounds__(512) void k_scan2(const int* __restrict__ bsum, int* __restrict__ boff, int nb) {
    __shared__ int sm[512];
    int t = threadIdx.x;
    int v = (t < nb) ? bsum[t] : 0;
    sm[t] = v;
    __syncthreads();
    int acc = v;
    for (int off = 1; off < 512; off <<= 1) {
        int u = (t >= off) ? sm[t - off] : 0;
        __syncthreads();
        acc += u;
        sm[t] = acc;
        __syncthreads();
    }
    if (t < nb) boff[t] = acc - v;
}

__global__ __launch_bounds__(256) void k_scan3(const int* __restrict__ deg, const int* __restrict__ partial,
                                               const int* __restrict__ boff, int* __restrict__ rowptr,
                                               int* __restrict__ cursor, float* __restrict__ dinv,
                                               int n, int e) {
    int i = blockIdx.x * 256 + threadIdx.x;
    if (i >= n) return;
    int excl = boff[blockIdx.x] + partial[i] - deg[i];
    rowptr[i] = excl;
    cursor[i] = excl;
    dinv[i] = rsqrtf((float)(deg[i] + 1));
    if (i == 0) rowptr[n] = e;
}

// ---------------- per-bucket CSR fill (writes stay in an ~8KB L2-local region) ----------------
__global__ __launch_bounds__(256) void k_bfill(const int2* __restrict__ pairs, const int* __restrict__ bo,
                                               int* __restrict__ cursor, int* __restrict__ csr_src) {
    int b = blockIdx.x;
    int beg = bo[b], end = bo[b + 1];
    for (int idx = beg + threadIdx.x; idx < end; idx += 256) {
        int2 pr = pairs[idx];
        int p = atomicAdd(&cursor[pr.y], 1);
        csr_src[p] = pr.x;
    }
}

// ---------------- GEMM1 via split-bf16 3-pass MFMA ----------------
// hs[i][f] = bf16( dinv[i] * sum_k x[i][k]*W1[f][k] ),  x = xhi+xlo, w = whi+wlo
// C ~= xhi*whi + xhi*wlo + xlo*whi  (lo*lo dropped, ~2^-18 rel)
// Block tile 128(M) x 128(N) x 32(K), 4 waves, wave = 4m x 4n frags of 16x16x32.
__global__ __launch_bounds__(256) void k_gemm(const float* __restrict__ x, const float* __restrict__ W1,
                                              const float* __restrict__ dinv,
                                              unsigned short* __restrict__ hs, int n) {
    __shared__ unsigned short Ahi[128][40], Alo[128][40];   // rows padded to 80B
    __shared__ unsigned short Bhi[128][40], Blo[128][40];
    const int tid = threadIdx.x;
    const int i0 = blockIdx.x * 128;
    const int l  = tid & 63;
    const int w  = tid >> 6;
    const int m0 = (w & 1) << 6;     // 0 or 64
    const int n0 = (w >> 1) << 6;    // 0 or 64
    const int fr = l & 15;           // frag row/col within tile
    const int kg = l >> 4;           // k-group 0..3

    f32x4 acc[4][4] = {};

    const int r0 = tid >> 3;         // 0..31
    const int c4 = (tid & 7) << 2;   // 0,4,...,28

    for (int kb = 0; kb < FIN; kb += 32) {
        // stage x tile (128 x 32) and W tile (128 x 32), fp32 -> bf16 hi/lo
        #pragma unroll
        for (int rr = 0; rr < 4; ++rr) {
            int row = r0 + rr * 32;
            int gi = i0 + row;
            float4 xv = {0.f, 0.f, 0.f, 0.f};
            if (gi < n) xv = *(const float4*)&x[(size_t)gi * FIN + kb + c4];
            float4 wv = *(const float4*)&W1[(size_t)row * FIN + kb + c4];
            unsigned short h0, l0;
            split_bf16(xv.x, h0, l0); Ahi[row][c4 + 0] = h0; Alo[row][c4 + 0] = l0;
            split_bf16(xv.y, h0, l0); Ahi[row][c4 + 1] = h0; Alo[row][c4 + 1] = l0;
            split_bf16(xv.z, h0, l0); Ahi[row][c4 + 2] = h0; Alo[row][c4 + 2] = l0;
            split_bf16(xv.w, h0, l0); Ahi[row][c4 + 3] = h0; Alo[row][c4 + 3] = l0;
            split_bf16(wv.x, h0, l0); Bhi[row][c4 + 0] = h0; Blo[row][c4 + 0] = l0;
            split_bf16(wv.y, h0, l0); Bhi[row][c4 + 1] = h0; Blo[row][c4 + 1] = l0;
            split_bf16(wv.z, h0, l0); Bhi[row][c4 + 2] = h0; Blo[row][c4 + 2] = l0;
            split_bf16(wv.w, h0, l0); Bhi[row][c4 + 3] = h0; Blo[row][c4 + 3] = l0;
        }
        __syncthreads();

        short8v ah[4], al[4];
        #pragma unroll
        for (int mt = 0; mt < 4; ++mt) {
            ah[mt] = *(const short8v*)&Ahi[m0 + mt * 16 + fr][kg * 8];
            al[mt] = *(const short8v*)&Alo[m0 + mt * 16 + fr][kg * 8];
        }
        #pragma unroll
        for (int nt = 0; nt < 4; ++nt) {
            short8v bh = *(const short8v*)&Bhi[n0 + nt * 16 + fr][kg * 8];
            short8v bl = *(const short8v*)&Blo[n0 + nt * 16 + fr][kg * 8];
            #pragma unroll
            for (int mt = 0; mt < 4; ++mt) {
                acc[mt][nt] = __builtin_amdgcn_mfma_f32_16x16x32_bf16(al[mt], bh, acc[mt][nt], 0, 0, 0);
                acc[mt][nt] = __builtin_amdgcn_mfma_f32_16x16x32_bf16(ah[mt], bl, acc[mt][nt], 0, 0, 0);
                acc[mt][nt] = __builtin_amdgcn_mfma_f32_16x16x32_bf16(ah[mt], bh, acc[mt][nt], 0, 0, 0);
            }
        }
        __syncthreads();
    }

    // epilogue: D(m,n): row = kg*4 + reg, col = fr (verified m89/m91 layout)
    #pragma unroll
    for (int mt = 0; mt < 4; ++mt) {
        int rbase = i0 + m0 + mt * 16 + kg * 4;
        float4 dv = {0.f, 0.f, 0.f, 0.f};
        if (rbase < n) dv = *(const float4*)&dinv[rbase];   // rbase is 4-aligned; tail guarded below
        #pragma unroll
        for (int nt = 0; nt < 4; ++nt) {
            f32x4 c = acc[mt][nt];
            int col = n0 + nt * 16 + fr;
            #pragma unroll
            for (int r = 0; r < 4; ++r) {
                int gi = rbase + r;
                if (gi < n) {
                    float di = ((const float*)&dv)[r];
                    hs[(size_t)gi * HID + col] = f2bf(((const float*)&c)[r] * di);
                }
            }
        }
    }
}

// ---------------- layer-1 aggregation fused with layer-2 dot ----------------
__global__ __launch_bounds__(256) void k_agg1(const unsigned int* __restrict__ hs,
                                              const int* __restrict__ rowptr,
                                              const int* __restrict__ csr_src,
                                              const float* __restrict__ dinv,
                                              const float* __restrict__ b1, const float* __restrict__ W2,
                                              float* __restrict__ zs, int n) {
    int i = (blockIdx.x << 2) + (threadIdx.x >> 6);
    if (i >= n) return;
    const int lane = threadIdx.x & 63;

    unsigned int sv = hs[(i << 6) + lane];                 // self-loop term
    float ax = __uint_as_float(sv << 16);
    float ay = __uint_as_float(sv & 0xffff0000u);

    int e = rowptr[i];
    const int end = rowptr[i + 1];
    while (e < end) {
        int cnt = end - e;
        if (cnt > 64) cnt = 64;
        int sidx = (lane < cnt) ? csr_src[e + lane] : 0;
        int j = 0;
        for (; j + 2 <= cnt; j += 2) {
            int s0 = __shfl(sidx, j, 64);
            int s1 = __shfl(sidx, j + 1, 64);
            unsigned int v0 = hs[(s0 << 6) + lane];
            unsigned int v1 = hs[(s1 << 6) + lane];
            ax += __uint_as_float(v0 << 16);
            ay += __uint_as_float(v0 & 0xffff0000u);
            ax += __uint_as_float(v1 << 16);
            ay += __uint_as_float(v1 & 0xffff0000u);
        }
        if (j < cnt) {
            int s0 = __shfl(sidx, j, 64);
            unsigned int v0 = hs[(s0 << 6) + lane];
            ax += __uint_as_float(v0 << 16);
            ay += __uint_as_float(v0 & 0xffff0000u);
        }
        e += cnt;
    }
    float di = dinv[i];
    float2 bb = ((const float2*)b1)[lane];
    float h0 = fmaxf(ax * di + bb.x, 0.f);
    float h1 = fmaxf(ay * di + bb.y, 0.f);
    float2 w2 = ((const float2*)W2)[lane];
    float z = h0 * w2.x + h1 * w2.y;
    #pragma unroll
    for (int off = 32; off; off >>= 1) z += __shfl_xor(z, off, 64);
    if (lane == 0) zs[i] = z * di;
}

// ---------------- layer-2 aggregation ----------------
__global__ void k_agg2(const float* __restrict__ zs, const int* __restrict__ rowptr,
                       const int* __restrict__ csr_src, const float* __restrict__ dinv,
                       const float* __restrict__ b2, float* __restrict__ out, int n) {
    int i = blockIdx.x * blockDim.x + threadIdx.x;
    if (i >= n) return;
    float acc = zs[i];
    int beg = rowptr[i], end = rowptr[i + 1];
    for (int e = beg; e < end; ++e) acc += zs[csr_src[e]];
    out[i] = acc * dinv[i] + b2[0];
}

extern "C" void kernel_launch(void* const* d_in, const int* in_sizes, int n_in,
                              void* d_out, int out_size, void* d_ws, size_t ws_size,
                              hipStream_t stream) {
    const float* x  = (const float*)d_in[0];
    const int*   ei = (const int*)d_in[1];
    const float* W1 = (const float*)d_in[2];
    const float* b1 = (const float*)d_in[3];
    const float* W2 = (const float*)d_in[4];
    const float* b2 = (const float*)d_in[5];
    float* out = (float*)d_out;

    const int n = in_sizes[0] / FIN;
    const int e = in_sizes[1] / 2;
    const int* src = ei;
    const int* dst = ei + e;
    const int nbk = (n + (1 << BSH) - 1) >> BSH;   // 782 buckets

    char* p = (char*)d_ws;
    auto carve = [&](size_t bytes) { char* q = p; p += (bytes + 255) & ~(size_t)255; return q; };
    int*            deg     = (int*)carve((size_t)n * 4);
    int*            bcnt    = (int*)carve(4096);
    int*            partial = (int*)carve((size_t)n * 4);
    int*            bsum    = (int*)carve(4096);
    int*            boff    = (int*)carve(4096);
    int*            bo      = (int*)carve(8192);
    int*            bcur    = (int*)carve(4096);
    int*            rowptr  = (int*)carve((size_t)(n + 1) * 4);
    int*            cursor  = (int*)carve((size_t)n * 4);
    float*          dinv    = (float*)carve((size_t)n * 4);
    int*            csr     = (int*)carve((size_t)e * 4);
    int2*           pairs   = (int2*)carve((size_t)e * 8);
    unsigned short* hs      = (unsigned short*)carve((size_t)n * HID * 2);
    float*          zs      = (float*)carve((size_t)n * 4);

    hipMemsetAsync(deg, 0, (size_t)n * 4, stream);
    hipMemsetAsync(bcnt, 0, 4096, stream);

    const int nb = (n + 255) / 256;
    k_deg  <<<(e + 255) / 256, 256, 0, stream>>>(dst, deg, bcnt, e);
    k_bscan<<<1, 1024, 0, stream>>>(bcnt, bo, bcur, nbk, e);
    k_scan1<<<nb, 256, 0, stream>>>(deg, partial, bsum, n);
    k_scan2<<<1, 512, 0, stream>>>(bsum, boff, nb);
    k_scan3<<<nb, 256, 0, stream>>>(deg, partial, boff, rowptr, cursor, dinv, n, e);
    k_pair <<<(e + 255) / 256, 256, 0, stream>>>(src, dst, bcur, pairs, e);
    k_bfill<<<nbk, 256, 0, stream>>>(pairs, bo, cursor, csr);
    k_gemm <<<(n + 127) / 128, 256, 0, stream>>>(x, W1, dinv, hs, n);
    k_agg1 <<<(n + 3) / 4, 256, 0, stream>>>((const unsigned int*)hs, rowptr, csr, dinv, b1, W2, zs, n);
    k_agg2 <<<(n + 255) / 256, 256, 0, stream>>>(zs, rowptr, csr, dinv, b2, out, n);
}

// Round 4
// 224.446 us; speedup vs baseline: 4.5861x; 4.5861x over previous
//
#include <hip/hip_runtime.h>
#include <hip/hip_bf16.h>

#define FIN 256
#define HID 128
#define BSH 7            // bucket = dst >> 7 (128 nodes/bucket)
#define NBK_MAX 1024
#define EPB 4096         // edges per block in hist/pair kernels

typedef __attribute__((ext_vector_type(8))) short short8v;   // bf16x8 MFMA frag
typedef __attribute__((ext_vector_type(4))) float f32x4;     // MFMA acc

static __device__ __forceinline__ unsigned short f2bf(float f) {
    unsigned int u = __float_as_uint(f);
    u += 0x7fffu + ((u >> 16) & 1u);   // RNE
    return (unsigned short)(u >> 16);
}
static __device__ __forceinline__ void split_bf16(float f, unsigned short& hi, unsigned short& lo) {
    unsigned int u = __float_as_uint(f);
    unsigned int uh = (u + (0x7fffu + ((u >> 16) & 1u))) & 0xffff0000u;
    hi = (unsigned short)(uh >> 16);
    float fl = f - __uint_as_float(uh);
    unsigned int ul = __float_as_uint(fl);
    lo = (unsigned short)((ul + (0x7fffu + ((ul >> 16) & 1u))) >> 16);
}

// ---------------- bucket histogram via LDS ----------------
__global__ __launch_bounds__(256) void k_hist(const int* __restrict__ dst, int* __restrict__ bcnt,
                                              int nbk, int e) {
    __shared__ int cnt[NBK_MAX];
    int t = threadIdx.x;
    for (int b = t; b < nbk; b += 256) cnt[b] = 0;
    __syncthreads();
    int e0 = blockIdx.x * EPB;
    #pragma unroll
    for (int j = 0; j < EPB; j += 256) {
        int idx = e0 + j + t;
        if (idx < e) atomicAdd(&cnt[dst[idx] >> BSH], 1);
    }
    __syncthreads();
    for (int b = t; b < nbk; b += 256)
        if (cnt[b]) atomicAdd(&bcnt[b], cnt[b]);
}

// ---------------- bucket scan (single block) ----------------
__global__ __launch_bounds__(1024) void k_bscan(const int* __restrict__ bcnt, int* __restrict__ bo,
                                                int* __restrict__ bcur, int nbk, int e) {
    __shared__ int sm[1024];
    int t = threadIdx.x;
    int v = (t < nbk) ? bcnt[t] : 0;
    sm[t] = v;
    __syncthreads();
    int acc = v;
    for (int off = 1; off < 1024; off <<= 1) {
        int u = (t >= off) ? sm[t - off] : 0;
        __syncthreads();
        acc += u;
        sm[t] = acc;
        __syncthreads();
    }
    if (t < nbk) { bo[t] = acc - v; bcur[t] = acc - v; }
    if (t == 0) bo[nbk] = e;
}

// ---------------- two-phase pair scatter (LDS counts, 1 global atomic per block-bucket) ----------------
__global__ __launch_bounds__(256) void k_pair2(const int* __restrict__ src, const int* __restrict__ dst,
                                               int* __restrict__ bcur, int2* __restrict__ pairs,
                                               int nbk, int e) {
    __shared__ int cnt[NBK_MAX];
    __shared__ int base[NBK_MAX];
    const int t = threadIdx.x;
    for (int b = t; b < nbk; b += 256) cnt[b] = 0;
    __syncthreads();
    const int e0 = blockIdx.x * EPB;
    int s[16], d[16], lo[16];
    #pragma unroll
    for (int j = 0; j < 16; ++j) {
        int idx = e0 + j * 256 + t;
        if (idx < e) {
            s[j] = src[idx];
            d[j] = dst[idx];
            lo[j] = atomicAdd(&cnt[d[j] >> BSH], 1);
        }
    }
    __syncthreads();
    for (int b = t; b < nbk; b += 256)
        base[b] = cnt[b] ? atomicAdd(&bcur[b], cnt[b]) : 0;
    __syncthreads();
    #pragma unroll
    for (int j = 0; j < 16; ++j) {
        int idx = e0 + j * 256 + t;
        if (idx < e) pairs[base[d[j] >> BSH] + lo[j]] = make_int2(s[j], d[j]);
    }
}

// ---------------- per-bucket degree (LDS histogram, plain stores) ----------------
__global__ __launch_bounds__(256) void k_bdeg(const int2* __restrict__ pairs, const int* __restrict__ bo,
                                              int* __restrict__ deg, int n) {
    __shared__ int cnt[128];
    const int b = blockIdx.x, t = threadIdx.x;
    if (t < 128) cnt[t] = 0;
    __syncthreads();
    int beg = bo[b], end = bo[b + 1];
    for (int i = beg + t; i < end; i += 256) atomicAdd(&cnt[pairs[i].y & 127], 1);
    __syncthreads();
    int node = (b << BSH) + t;
    if (t < 128 && node < n) deg[node] = cnt[t];
}

// ---------------- 3-kernel exclusive scan over deg ----------------
__global__ __launch_bounds__(256) void k_scan1(const int* __restrict__ deg, int* __restrict__ partial,
                                               int* __restrict__ bsum, int n) {
    __shared__ int sm[256];
    int t = threadIdx.x;
    int i = blockIdx.x * 256 + t;
    int v = (i < n) ? deg[i] : 0;
    sm[t] = v;
    __syncthreads();
    int acc = v;
    for (int off = 1; off < 256; off <<= 1) {
        int u = (t >= off) ? sm[t - off] : 0;
        __syncthreads();
        acc += u;
        sm[t] = acc;
        __syncthreads();
    }
    if (i < n) partial[i] = acc;
    if (t == 255) bsum[blockIdx.x] = acc;
}

__global__ __launch_bounds__(512) void k_scan2(const int* __restrict__ bsum, int* __restrict__ boff, int nb) {
    __shared__ int sm[512];
    int t = threadIdx.x;
    int v = (t < nb) ? bsum[t] : 0;
    sm[t] = v;
    __syncthreads();
    int acc = v;
    for (int off = 1; off < 512; off <<= 1) {
        int u = (t >= off) ? sm[t - off] : 0;
        __syncthreads();
        acc += u;
        sm[t] = acc;
        __syncthreads();
    }
    if (t < nb) boff[t] = acc - v;
}

__global__ __launch_bounds__(256) void k_scan3(const int* __restrict__ deg, const int* __restrict__ partial,
                                               const int* __restrict__ boff, int* __restrict__ rowptr,
                                               float* __restrict__ dinv, int n, int e) {
    int i = blockIdx.x * 256 + threadIdx.x;
    if (i >= n) return;
    rowptr[i] = boff[blockIdx.x] + partial[i] - deg[i];
    dinv[i] = rsqrtf((float)(deg[i] + 1));
    if (i == 0) rowptr[n] = e;
}

// ---------------- per-bucket CSR fill (LDS cursors seeded from rowptr) ----------------
__global__ __launch_bounds__(256) void k_bfill(const int2* __restrict__ pairs, const int* __restrict__ bo,
                                               const int* __restrict__ rowptr, int* __restrict__ csr_src,
                                               int n) {
    __shared__ int cur[128];
    const int b = blockIdx.x, t = threadIdx.x;
    int node = (b << BSH) + t;
    if (t < 128) cur[t] = (node < n) ? rowptr[node] : 0;
    __syncthreads();
    int beg = bo[b], end = bo[b + 1];
    for (int i = beg + t; i < end; i += 256) {
        int2 pr = pairs[i];
        int p = atomicAdd(&cur[pr.y & 127], 1);
        csr_src[p] = pr.x;
    }
}

// ---------------- W1 pre-split (once) ----------------
__global__ void k_wsplit(const float* __restrict__ W1, unsigned short* __restrict__ Whi,
                         unsigned short* __restrict__ Wlo, int total) {
    int i = blockIdx.x * 256 + threadIdx.x;
    if (i < total) {
        unsigned short h, l;
        split_bf16(W1[i], h, l);
        Whi[i] = h; Wlo[i] = l;
    }
}

// ---------------- GEMM1 via split-bf16 3-pass MFMA ----------------
// Block tile 128(M) x 128(N) x 32(K), 4 waves, wave = 4m x 4n frags of 16x16x32.
__global__ __launch_bounds__(256) void k_gemm(const float* __restrict__ x,
                                              const unsigned short* __restrict__ Whi,
                                              const unsigned short* __restrict__ Wlo,
                                              const float* __restrict__ dinv,
                                              unsigned short* __restrict__ hs, int n) {
    __shared__ unsigned short Ahi[128][40], Alo[128][40];   // row stride 80B (16B-aligned)
    __shared__ unsigned short Bhi[128][40], Blo[128][40];
    const int tid = threadIdx.x;
    const int i0 = blockIdx.x * 128;
    const int l  = tid & 63;
    const int w  = tid >> 6;
    const int m0 = (w & 1) << 6;
    const int n0 = (w >> 1) << 6;
    const int fr = l & 15;
    const int kg = l >> 4;

    f32x4 acc[4][4] = {};

    const int r0 = tid >> 3;         // 0..31
    const int c4 = (tid & 7) << 2;   // 0,4,...,28

    for (int kb = 0; kb < FIN; kb += 32) {
        #pragma unroll
        for (int rr = 0; rr < 4; ++rr) {
            int row = r0 + rr * 32;
            int gi = i0 + row;
            float4 xv = {0.f, 0.f, 0.f, 0.f};
            if (gi < n) xv = *(const float4*)&x[(size_t)gi * FIN + kb + c4];
            ushort4 xh, xl;
            split_bf16(xv.x, xh.x, xl.x);
            split_bf16(xv.y, xh.y, xl.y);
            split_bf16(xv.z, xh.z, xl.z);
            split_bf16(xv.w, xh.w, xl.w);
            *(ushort4*)&Ahi[row][c4] = xh;
            *(ushort4*)&Alo[row][c4] = xl;
            *(ushort4*)&Bhi[row][c4] = *(const ushort4*)&Whi[row * FIN + kb + c4];
            *(ushort4*)&Blo[row][c4] = *(const ushort4*)&Wlo[row * FIN + kb + c4];
        }
        __syncthreads();

        short8v ah[4], al[4];
        #pragma unroll
        for (int mt = 0; mt < 4; ++mt) {
            ah[mt] = *(const short8v*)&Ahi[m0 + mt * 16 + fr][kg * 8];
            al[mt] = *(const short8v*)&Alo[m0 + mt * 16 + fr][kg * 8];
        }
        #pragma unroll
        for (int nt = 0; nt < 4; ++nt) {
            short8v bh = *(const short8v*)&Bhi[n0 + nt * 16 + fr][kg * 8];
            short8v bl = *(const short8v*)&Blo[n0 + nt * 16 + fr][kg * 8];
            #pragma unroll
            for (int mt = 0; mt < 4; ++mt) {
                acc[mt][nt] = __builtin_amdgcn_mfma_f32_16x16x32_bf16(al[mt], bh, acc[mt][nt], 0, 0, 0);
                acc[mt][nt] = __builtin_amdgcn_mfma_f32_16x16x32_bf16(ah[mt], bl, acc[mt][nt], 0, 0, 0);
                acc[mt][nt] = __builtin_amdgcn_mfma_f32_16x16x32_bf16(ah[mt], bh, acc[mt][nt], 0, 0, 0);
            }
        }
        __syncthreads();
    }

    // D(m,n): row = kg*4 + reg, col = fr
    #pragma unroll
    for (int mt = 0; mt < 4; ++mt) {
        int rbase = i0 + m0 + mt * 16 + kg * 4;
        float4 dv = {0.f, 0.f, 0.f, 0.f};
        if (rbase < n) dv = *(const float4*)&dinv[rbase];
        #pragma unroll
        for (int nt = 0; nt < 4; ++nt) {
            f32x4 c = acc[mt][nt];
            int col = n0 + nt * 16 + fr;
            #pragma unroll
            for (int r = 0; r < 4; ++r) {
                int gi = rbase + r;
                if (gi < n) {
                    float di = ((const float*)&dv)[r];
                    hs[(size_t)gi * HID + col] = f2bf(((const float*)&c)[r] * di);
                }
            }
        }
    }
}

// ---------------- layer-1 aggregation fused with layer-2 dot ----------------
__global__ __launch_bounds__(256) void k_agg1(const unsigned int* __restrict__ hs,
                                              const int* __restrict__ rowptr,
                                              const int* __restrict__ csr_src,
                                              const float* __restrict__ dinv,
                                              const float* __restrict__ b1, const float* __restrict__ W2,
                                              float* __restrict__ zs, int n) {
    int i = (blockIdx.x << 2) + (threadIdx.x >> 6);
    if (i >= n) return;
    const int lane = threadIdx.x & 63;

    unsigned int sv = hs[(i << 6) + lane];                 // self-loop term
    float ax = __uint_as_float(sv << 16);
    float ay = __uint_as_float(sv & 0xffff0000u);

    int e = rowptr[i];
    const int end = rowptr[i + 1];
    while (e < end) {
        int cnt = end - e;
        if (cnt > 64) cnt = 64;
        int sidx = (lane < cnt) ? csr_src[e + lane] : 0;
        int j = 0;
        for (; j + 2 <= cnt; j += 2) {
            int s0 = __shfl(sidx, j, 64);
            int s1 = __shfl(sidx, j + 1, 64);
            unsigned int v0 = hs[(s0 << 6) + lane];
            unsigned int v1 = hs[(s1 << 6) + lane];
            ax += __uint_as_float(v0 << 16);
            ay += __uint_as_float(v0 & 0xffff0000u);
            ax += __uint_as_float(v1 << 16);
            ay += __uint_as_float(v1 & 0xffff0000u);
        }
        if (j < cnt) {
            int s0 = __shfl(sidx, j, 64);
            unsigned int v0 = hs[(s0 << 6) + lane];
            ax += __uint_as_float(v0 << 16);
            ay += __uint_as_float(v0 & 0xffff0000u);
        }
        e += cnt;
    }
    float di = dinv[i];
    float2 bb = ((const float2*)b1)[lane];
    float h0 = fmaxf(ax * di + bb.x, 0.f);
    float h1 = fmaxf(ay * di + bb.y, 0.f);
    float2 w2 = ((const float2*)W2)[lane];
    float z = h0 * w2.x + h1 * w2.y;
    #pragma unroll
    for (int off = 32; off; off >>= 1) z += __shfl_xor(z, off, 64);
    if (lane == 0) zs[i] = z * di;
}

// ---------------- layer-2 aggregation ----------------
__global__ void k_agg2(const float* __restrict__ zs, const int* __restrict__ rowptr,
                       const int* __restrict__ csr_src, const float* __restrict__ dinv,
                       const float* __restrict__ b2, float* __restrict__ out, int n) {
    int i = blockIdx.x * blockDim.x + threadIdx.x;
    if (i >= n) return;
    float acc = zs[i];
    int beg = rowptr[i], end = rowptr[i + 1];
    for (int e = beg; e < end; ++e) acc += zs[csr_src[e]];
    out[i] = acc * dinv[i] + b2[0];
}

extern "C" void kernel_launch(void* const* d_in, const int* in_sizes, int n_in,
                              void* d_out, int out_size, void* d_ws, size_t ws_size,
                              hipStream_t stream) {
    const float* x  = (const float*)d_in[0];
    const int*   ei = (const int*)d_in[1];
    const float* W1 = (const float*)d_in[2];
    const float* b1 = (const float*)d_in[3];
    const float* W2 = (const float*)d_in[4];
    const float* b2 = (const float*)d_in[5];
    float* out = (float*)d_out;

    const int n = in_sizes[0] / FIN;
    const int e = in_sizes[1] / 2;
    const int* src = ei;
    const int* dst = ei + e;
    const int nbk = (n + (1 << BSH) - 1) >> BSH;

    char* p = (char*)d_ws;
    auto carve = [&](size_t bytes) { char* q = p; p += (bytes + 255) & ~(size_t)255; return q; };
    int*            deg     = (int*)carve((size_t)n * 4);
    int*            bcnt    = (int*)carve((size_t)NBK_MAX * 4);
    int*            partial = (int*)carve((size_t)n * 4);
    int*            bsum    = (int*)carve(4096);
    int*            boff    = (int*)carve(4096);
    int*            bo      = (int*)carve((size_t)(NBK_MAX + 1) * 4);
    int*            bcur    = (int*)carve((size_t)NBK_MAX * 4);
    int*            rowptr  = (int*)carve((size_t)(n + 1) * 4);
    float*          dinv    = (float*)carve((size_t)n * 4);
    int*            csr     = (int*)carve((size_t)e * 4);
    int2*           pairs   = (int2*)carve((size_t)e * 8);
    unsigned short* hs      = (unsigned short*)carve((size_t)n * HID * 2);
    float*          zs      = (float*)carve((size_t)n * 4);
    unsigned short* Whi     = (unsigned short*)carve((size_t)HID * FIN * 2);
    unsigned short* Wlo     = (unsigned short*)carve((size_t)HID * FIN * 2);

    hipMemsetAsync(bcnt, 0, (size_t)NBK_MAX * 4, stream);

    const int nb  = (n + 255) / 256;
    const int neb = (e + EPB - 1) / EPB;
    k_wsplit<<<(HID * FIN + 255) / 256, 256, 0, stream>>>(W1, Whi, Wlo, HID * FIN);
    k_hist <<<neb, 256, 0, stream>>>(dst, bcnt, nbk, e);
    k_bscan<<<1, 1024, 0, stream>>>(bcnt, bo, bcur, nbk, e);
    k_pair2<<<neb, 256, 0, stream>>>(src, dst, bcur, pairs, nbk, e);
    k_bdeg <<<nbk, 256, 0, stream>>>(pairs, bo, deg, n);
    k_scan1<<<nb, 256, 0, stream>>>(deg, partial, bsum, n);
    k_scan2<<<1, 512, 0, stream>>>(bsum, boff, nb);
    k_scan3<<<nb, 256, 0, stream>>>(deg, partial, boff, rowptr, dinv, n, e);
    k_bfill<<<nbk, 256, 0, stream>>>(pairs, bo, rowptr, csr, n);
    k_gemm <<<(n + 127) / 128, 256, 0, stream>>>(x, Whi, Wlo, dinv, hs, n);
    k_agg1 <<<(n + 3) / 4, 256, 0, stream>>>((const unsigned int*)hs, rowptr, csr, dinv, b1, W2, zs, n);
    k_agg2 <<<(n + 255) / 256, 256, 0, stream>>>(zs, rowptr, csr, dinv, b2, out, n);
}